// Round 7
// baseline (307.191 us; speedup 1.0000x reference)
//
#include <hip/hip_runtime.h>

// BoostedNeuralLDPCDecoder — MI355X HIP implementation (round 11)
//
// Rounds 9/10 showed the fused LLC-direct design is TRAFFIC-bound: 326 MB of
// coherence-point traffic per dispatch (~2 TB/s sustained), and ILP tuning
// moved nothing. The traffic is structural to the cross-block protocol, so
// this round removes the protocol entirely:
//
//   ONE 1024-thread workgroup per batch b (64 blocks, 1 per CU by LDS size).
//   * c2v slice [E+1][Z] int8 = 141.7 KB lives in LDS (dynamic).
//   * tot slice [N][Z] f32 = 104 KB is block-private global: normal cached
//     loads/stores, same-CU coherence, no flags/fences/barriers/memsets.
//   * all 5 iterations inside the block with __syncthreads() only.
//   * HBM traffic collapses to xa (6.7 MB) + out (33.4 MB).
//   * VN: proven 17x64 tile transpose; 4 teams x 256 threads, 6 tiles each,
//     lockstep block-wide syncs.
// Arithmetic verbatim round-4 (absmax 0.0 must be preserved; int message
// sums are order-independent -> bit-exact under any gather-slot order).
//
// LDS budget: 141,696 (dyn c2v) + 17,680 (tiles) + 3,264 (u16 sev) + 272
// (sdeg) = 162,912 B <= 163,840 B per CU.

#define ITERS 5
#define Nn 68
#define Mm 46
#define Zz 384
#define Ee 368
#define Bb 64
#define Kk 8          // edges per CN (E/M)
#define PADD 24       // padded max VN degree
#define BIGF 1e9f

#define BLKT 1024
#define CNU (Mm*Zz)                      // 17,664 check-lane units per batch
#define OUT_ITER ((size_t)Bb*Zz*Nn)
#define DYN_LDS ((Ee+1)*Zz)              // 141,696 B c2v slice (+zero row E)

// ---- min-sum tail: round-4 arithmetic, LDS byte stores ----
__device__ __forceinline__ void minsum_store(
    const float v[Kk], const int off[Kk], float m1, unsigned sflip,
    float w, signed char* __restrict__ c2v)
{
    // min2 over entries whose |v| != min1 (reference tie semantics, BIG if none)
    float m2 = BIGF;
    #pragma unroll
    for (int k = 0; k < Kk; k++) {
        float mag = fabsf(v[k]);
        if (mag != m1) m2 = fminf(m2, mag);
    }
    #pragma unroll
    for (int k = 0; k < Kk; k++) {
        float mag  = fabsf(v[k]);
        float emin = (mag == m1) ? m2 : m1;
        unsigned neg = sflip ^ ((v[k] < 0.0f) ? 1u : 0u);  // csign * own_sign
        float ext = neg ? -emin : emin;
        // _qms5(w * ext): forward == clip(rintf(2*x)/2, +-7.5); store 2*q as int8
        float r = rintf(w * ext * 2.0f);
        r = fminf(15.0f, fmaxf(-15.0f, r));
        c2v[off[k]] = (signed char)(int)r;   // ds_write_b8
    }
}

// ---- CN phase: units u = (cn*Z + zc); thread handles u = tid + i*1024 ----
// src is the per-batch [N][Z] belief array: xa slice (it 0) or tot slice.
template<bool FIRST>
__device__ __forceinline__ void cn_pass(
    const float* __restrict__ src, signed char* __restrict__ c2v,
    const int* __restrict__ edge_vn, const int* __restrict__ edge_shift,
    float w, int tid)
{
    const int nu = (tid < CNU - 17 * BLKT) ? 18 : 17;   // 17,664 = 17*1024+256
    int u = tid;
    for (int i = 0; i < nu; ++i, u += BLKT) {
        // wave's 64 consecutive u lie in one cn (64 | 384, base 64-aligned)
        const int cn = __builtin_amdgcn_readfirstlane(u) / Zz;
        const int zc = u - cn * Zz;      // per-lane lifted row

        float v[Kk];
        int   off[Kk];
        float m1 = BIGF;
        unsigned sflip = 0u;

        #pragma unroll
        for (int k = 0; k < Kk; k++) {
            int e  = cn + k * Mm;        // edges of this check (edge_cn = e % M)
            int sh = edge_shift[e];      // wave-uniform -> scalar load
            int n  = edge_vn[e];         // wave-uniform
            int z  = zc - sh;
            z += (z >> 31) & Zz;         // mod Z
            int o = e * Zz + z;          // LDS byte offset
            off[k] = o;
            float x = src[n * Zz + z];   // cached, block-private (L1/L2 hit)
            if (!FIRST) x -= 0.5f * (float)c2v[o];     // exact decode, 1 rounding
            x = fminf(20.0f, fmaxf(-20.0f, x));        // allowed_llr_range
            v[k] = x;
            if (x < 0.0f) sflip ^= 1u;
            m1 = fminf(m1, fabsf(x));
        }
        minsum_store(v, off, m1, sflip, w, c2v);
    }
}

// ---- VN phase: 4 teams x 256 threads; team = n-chunk, 6 z-tiles each ----
__device__ __forceinline__ void vn_pass(
    const float* __restrict__ xab, const signed char* __restrict__ c2v,
    float* __restrict__ totb, float* __restrict__ out_g,
    const unsigned short* __restrict__ sev, const int* __restrict__ sdeg,
    int write_tot, float (*tile)[65], int team, int ttid)
{
    const int wave = ttid >> 6;          // 0..3 within team
    const int lane = ttid & 63;
    const int n0 = team * 17;            // n-chunk per team (4 x 17 = 68)

    for (int zq = 0; zq < 6; ++zq) {
        const int z0 = zq * 64;
        const int z  = z0 + lane;

        for (int i = wave; i < 17; i += 4) {
            int n = __builtin_amdgcn_readfirstlane(n0 + i);
            int d = __builtin_amdgcn_readfirstlane(sdeg[n]);  // wave-uniform
            const unsigned short* vo = sev + n * PADD;
            int acc = 0;                 // sum of int8 messages (2x): exact
            #pragma unroll
            for (int j = 0; j < 8; j++)
                acc += (int)c2v[(int)vo[j] * Zz + z];         // ds_read_i8
            if (d > 8) {
                #pragma unroll
                for (int j = 8; j < 16; j++)
                    acc += (int)c2v[(int)vo[j] * Zz + z];
            }
            if (d > 16) {
                #pragma unroll
                for (int j = 16; j < PADD; j++)
                    acc += (int)c2v[(int)vo[j] * Zz + z];
            }
            float s = xab[n * Zz + z] + 0.5f * (float)acc;    // one rounding
            if (write_tot) totb[n * Zz + z] = s;              // cached store
            tile[i][lane] = s;
        }
        __syncthreads();                 // block-wide; all teams at same zq

        // out[it][b][z][n]: 64 z-rows x 17 contiguous floats (68 B segments);
        // the 4 teams' segments at each z are adjacent -> L2 write-merge
        float* dst = out_g + (size_t)z0 * Nn + n0;
        for (int idx = ttid; idx < 17 * 64; idx += 256) {
            int zz = idx / 17;
            int nn = idx - zz * 17;
            dst[(size_t)zz * Nn + nn] = tile[nn][zz];
        }
        __syncthreads();                 // tile reused by next zq
    }
}

__global__ __launch_bounds__(BLKT, 1) void fused_kernel(
    const float* __restrict__ xa, const float* __restrict__ cn_weight,
    const int* __restrict__ edge_vn, const int* __restrict__ edge_shift,
    float* __restrict__ tot, float* __restrict__ out)
{
    extern __shared__ signed char c2v[];         // [E+1][Z] bytes, row E = 0
    __shared__ float tile[4][17][65];            // per-team transpose tiles
    __shared__ unsigned short sev[Nn * PADD];    // per-VN edge index (dummy=Ee)
    __shared__ int sdeg[Nn];

    const int g   = blockIdx.x;                  // batch b
    const int tid = threadIdx.x;
    const int team = tid >> 8, ttid = tid & 255;

    // ---- per-block gather tables (order-independent -> bit-exact) ----
    for (int i = tid; i < Nn; i += BLKT) sdeg[i] = 0;
    for (int i = tid; i < Nn * PADD; i += BLKT) sev[i] = (unsigned short)Ee;
    __syncthreads();
    if (tid < Ee) {
        int n = edge_vn[tid];
        int slot = atomicAdd(&sdeg[n], 1);
        if (slot < PADD) sev[n * PADD + slot] = (unsigned short)tid;
    }
    // zero dummy row E (read by padded gather slots)
    {
        int* p = (int*)(c2v + Ee * Zz);
        for (int i = tid; i < Zz / 4; i += BLKT) p[i] = 0;
    }
    __syncthreads();

    const float* xab  = xa  + (size_t)g * Nn * Zz;   // [n][z] slice
    float*       totb = tot + (size_t)g * Nn * Zz;   // [n][z] slice (private)

    for (int it = 0; it < ITERS; ++it) {
        const float w = cn_weight[it];
        if (it == 0) cn_pass<true >(xab,  c2v, edge_vn, edge_shift, w, tid);
        else         cn_pass<false>(totb, c2v, edge_vn, edge_shift, w, tid);
        __syncthreads();                 // c2v (LDS) complete for VN
        vn_pass(xab, c2v, totb,
                out + (size_t)it * OUT_ITER + (size_t)g * Zz * Nn,
                sev, sdeg, (it != ITERS - 1) ? 1 : 0,
                tile[team], team, ttid);
        __syncthreads();                 // tot/tiles settled before next CN
    }
}

extern "C" void kernel_launch(void* const* d_in, const int* in_sizes, int n_in,
                              void* d_out, int out_size, void* d_ws, size_t ws_size,
                              hipStream_t stream) {
    const float* xa        = (const float*)d_in[0];  // [B][N][Z]
    const float* cn_weight = (const float*)d_in[1];  // [ITERS]
    const int*   edge_vn   = (const int*)d_in[2];    // [E]
    // d_in[3] = edge_cn: structurally e % M, not needed
    const int*   edge_shift= (const int*)d_in[4];    // [E]
    float* out = (float*)d_out;                      // [ITERS][B][Z][N]

    float* tot = (float*)d_ws;                       // [B][N][Z] private slices

    // allow >64 KB dynamic LDS (host-side, immediate, capture-safe); once
    static int inited = 0;
    if (!inited) {
        (void)hipFuncSetAttribute((const void*)fused_kernel,
                                  hipFuncAttributeMaxDynamicSharedMemorySize,
                                  DYN_LDS);
        inited = 1;
    }

    fused_kernel<<<dim3(Bb), dim3(BLKT), DYN_LDS, stream>>>(
        xa, cn_weight, edge_vn, edge_shift, tot, out);
}